// Round 8
// baseline (163.882 us; speedup 1.0000x reference)
//
#include <hip/hip_runtime.h>
#include <cstdint>

#define BATCH 4
#define TQ 256
#define TK 256
#define DIM 256
#define HD 256

typedef _Float16 f16x8 __attribute__((ext_vector_type(8)));
typedef float f32x4 __attribute__((ext_vector_type(4)));

union U4H8 { uint4 u; f16x8 v; };

__device__ __forceinline__ unsigned short f2h(float f) {
    _Float16 h = (_Float16)f;
    unsigned short u;
    __builtin_memcpy(&u, &h, 2);
    return u;
}

__device__ __forceinline__ float h2f(unsigned short u) {
    _Float16 h;
    __builtin_memcpy(&h, &u, 2);
    return (float)h;
}

__device__ __forceinline__ uint32_t pk2h(float a, float b) {
    auto r = __builtin_amdgcn_cvt_pkrtz(a, b);
    uint32_t w;
    __builtin_memcpy(&w, &r, 4);
    return w;
}

// pack: blocks 0..511   -> X = [queries; keys] split to f16 hi/lo (Xh, Xl)
//       blocks 512..639 -> W1T hi/lo transpose
//       blocks 640..703 -> W2T[n][c] = (f16)W2[c][n]
__global__ __launch_bounds__(256) void pack(
    const float* __restrict__ queries, const float* __restrict__ keys,
    const float* __restrict__ W1, const float* __restrict__ W2,
    unsigned short* __restrict__ Xh, unsigned short* __restrict__ Xl,
    unsigned short* __restrict__ W1Th, unsigned short* __restrict__ W1Tl,
    unsigned short* __restrict__ W2T) {
    int i = blockIdx.x;
    int t = threadIdx.x;
    if (i < 512) {   // ---- X hi/lo split, 4 floats/thread ----
        const float* src = (i < 256 ? queries : keys) + (((i & 255) * 256 + t) << 2);
        float4 v = *(const float4*)src;
        uint32_t h0 = pk2h(v.x, v.y), h1 = pk2h(v.z, v.w);
        float f0 = h2f((unsigned short)h0), f1 = h2f((unsigned short)(h0 >> 16));
        float f2 = h2f((unsigned short)h1), f3 = h2f((unsigned short)(h1 >> 16));
        uint32_t l0 = pk2h(v.x - f0, v.y - f1), l1 = pk2h(v.z - f2, v.w - f3);
        int o = i * 256 + t;
        ((uint2*)Xh)[o] = make_uint2(h0, h1);
        ((uint2*)Xl)[o] = make_uint2(l0, l1);
        return;
    }
    __shared__ float tile[32][33];
    int tx = t & 31, ty = t >> 5;
    if (i < 640) {   // ---- W1 transpose + hi/lo split: [512][256] -> [256][512] ----
        int bi = i - 512;
        int kt = (bi >> 3) * 32, nt = (bi & 7) * 32;
#pragma unroll
        for (int r = 0; r < 4; ++r)
            tile[ty + r * 8][tx] = W1[(kt + ty + r * 8) * HD + nt + tx];
        __syncthreads();
#pragma unroll
        for (int r = 0; r < 4; ++r) {
            float v = tile[tx][ty + r * 8];
            unsigned short h = f2h(v);
            int o = (nt + ty + r * 8) * 512 + kt + tx;
            W1Th[o] = h;
            W1Tl[o] = f2h(v - h2f(h));
        }
        return;
    }
    // ---- W2 transpose -> f16 ----
    int bi = i - 640;
    int tc = (bi & 7) * 32, tn = (bi >> 3) * 32;
#pragma unroll
    for (int r = 0; r < 4; ++r)
        tile[ty + r * 8][tx] = W2[(tc + ty + r * 8) * HD + tn + tx];
    __syncthreads();
#pragma unroll
    for (int r = 0; r < 4; ++r)
        W2T[(tn + ty + r * 8) * HD + tc + tx] = f2h(tile[tx][ty + r * 8]);
}

// qkh via MFMA with 3-term hi/lo split (effectively fp32-exact).
__global__ __launch_bounds__(256) void prep_mfma(
    const unsigned short* __restrict__ Xh, const unsigned short* __restrict__ Xl,
    const unsigned short* __restrict__ W1Th, const unsigned short* __restrict__ W1Tl,
    const float* __restrict__ b1, float* __restrict__ qkh) {
    int mblk = blockIdx.x >> 2, nblk = blockIdx.x & 3;
    int t = threadIdx.x, wid = t >> 6, lane = t & 63;
    int col = lane & 15, quad = lane >> 4;
    int arow = mblk * 64 + wid * 16 + col;
    bool isQ = mblk < 16;
    int koff = isQ ? 256 : 0;

    const uint4* axh = (const uint4*)(Xh + arow * DIM) + quad;
    const uint4* axl = (const uint4*)(Xl + arow * DIM) + quad;
    const uint4* pbh[4];
    const uint4* pbl[4];
    float b1v[4];
#pragma unroll
    for (int nt = 0; nt < 4; ++nt) {
        int n = nblk * 64 + nt * 16 + col;
        pbh[nt] = (const uint4*)(W1Th + n * 512 + koff) + quad;
        pbl[nt] = (const uint4*)(W1Tl + n * 512 + koff) + quad;
        b1v[nt] = isQ ? b1[n] : 0.f;
    }
    f32x4 acc[4] = {};
#pragma unroll
    for (int s = 0; s < 8; ++s) {
        U4H8 ah, al;
        ah.u = axh[s * 4];
        al.u = axl[s * 4];
#pragma unroll
        for (int nt = 0; nt < 4; ++nt) {
            U4H8 bh, bl;
            bh.u = pbh[nt][s * 4];
            bl.u = pbl[nt][s * 4];
            acc[nt] = __builtin_amdgcn_mfma_f32_16x16x32_f16(ah.v, bh.v, acc[nt], 0, 0, 0);
            acc[nt] = __builtin_amdgcn_mfma_f32_16x16x32_f16(al.v, bh.v, acc[nt], 0, 0, 0);
            acc[nt] = __builtin_amdgcn_mfma_f32_16x16x32_f16(ah.v, bl.v, acc[nt], 0, 0, 0);
        }
    }
#pragma unroll
    for (int nt = 0; nt < 4; ++nt)
#pragma unroll
        for (int r = 0; r < 4; ++r)
            qkh[(mblk * 64 + wid * 16 + quad * 4 + r) * HD + nblk * 64 + nt * 16 + col] =
                acc[nt][r] + b1v[nt];
}

// One block per (b,q), 512 threads = 8 waves; wave w owns n-slice of 32.
// acc[4][2]=32 regs -> fits __launch_bounds__(512,4) = 128 regs, 16 waves/CU.
// Staging split: wave w stages m-tile (w&3), k-steps (w>>2)*4..+4.
// Computes score row, softmax in-block, writes PROBS to global.
__global__ __launch_bounds__(512, 4) void mlp_scores(
    const float* __restrict__ qh, const float* __restrict__ kh,
    const unsigned short* __restrict__ W2T,
    const float* __restrict__ b2, const float* __restrict__ W3,
    const int* __restrict__ qlens, const int* __restrict__ klens,
    float* __restrict__ probs) {
    int bid = blockIdx.x;
    int b = bid >> 8;
    int q = bid & 255;
    int t = threadIdx.x;
    if (q >= qlens[b]) return;   // pv writes zeros for masked q rows
    int klen = klens[b];
    int nch = (klen + 63) >> 6;

    __shared__ uint4 Afrag[8][4][64];   // 32 KB, single buffer
    __shared__ float srow[TK];
    __shared__ float redm[8], reds[8];

    int wv = t >> 6, lane = t & 63;
    int col = lane & 15, quad = lane >> 4;

    // ---- B: wave wv covers n in [wv*32, wv*32+32) ----
    const uint4* w2r[2];
    float b2v[2], w3v[2];
#pragma unroll
    for (int nt = 0; nt < 2; ++nt) {
        int n = wv * 32 + nt * 16 + col;
        w2r[nt] = (const uint4*)(W2T + n * HD) + quad;  // pre-offset by c-octet
        b2v[nt] = b2[n];
        w3v[nt] = W3[n];
    }

    // ---- staging role ----
    int mt_s = wv & 3, s0 = (wv >> 2) << 2;
    int p = (mt_s << 4) | col;                    // A-row within chunk
    const float* qrow = qh + (b * TQ + q) * HD + quad * 8;   // b1 pre-folded
    const float* kbase = kh + (b * TK) * HD + quad * 8;

    if (t < TK) srow[t] = 0.f;

    for (int c = 0; c < nch; ++c) {
        if (c) __syncthreads();     // prior chunk's reads done before overwrite
        {   // ---- stage: 4 k-steps per thread ----
            const float* krow = kbase + (c * 64 + p) * HD;
            uint4* dst = &Afrag[s0][mt_s][lane];
#pragma unroll 2
            for (int s = 0; s < 4; ++s) {
                int c0 = (s0 + s) * 32;
                const float4 k0 = *(const float4*)(krow + c0);
                const float4 k1 = *(const float4*)(krow + c0 + 4);
                const float4 q0 = *(const float4*)(qrow + c0);
                const float4 q1 = *(const float4*)(qrow + c0 + 4);
                uint4 w;
                w.x = pk2h(fmaxf(k0.x + q0.x, 0.f), fmaxf(k0.y + q0.y, 0.f));
                w.y = pk2h(fmaxf(k0.z + q0.z, 0.f), fmaxf(k0.w + q0.w, 0.f));
                w.z = pk2h(fmaxf(k1.x + q1.x, 0.f), fmaxf(k1.y + q1.y, 0.f));
                w.w = pk2h(fmaxf(k1.z + q1.z, 0.f), fmaxf(k1.w + q1.w, 0.f));
                dst[s * 256] = w;
            }
        }
        __syncthreads();            // A tile visible

        f32x4 acc[4][2] = {};
        uint4 bst[2][2];
#pragma unroll
        for (int nt = 0; nt < 2; ++nt) bst[0][nt] = w2r[nt][0];
#pragma unroll
        for (int s = 0; s < 8; ++s) {
            int pp = s & 1;
            if (s < 7) {
#pragma unroll
                for (int nt = 0; nt < 2; ++nt)
                    bst[pp ^ 1][nt] = w2r[nt][(s + 1) * 4];
            }
#pragma unroll
            for (int mt = 0; mt < 4; ++mt) {
                U4H8 au;
                au.u = Afrag[s][mt][lane];
#pragma unroll
                for (int nt = 0; nt < 2; ++nt) {
                    U4H8 bu;
                    bu.u = bst[pp][nt];
                    acc[mt][nt] = __builtin_amdgcn_mfma_f32_16x16x32_f16(
                        au.v, bu.v, acc[mt][nt], 0, 0, 0);
                }
            }
        }

        // epilogue: relu(+b2)*W3, reduce over this wave's 32 n, atomic across waves
#pragma unroll
        for (int mt = 0; mt < 4; ++mt) {
            float part[4];
#pragma unroll
            for (int r = 0; r < 4; ++r) {
                float pa = 0.f;
#pragma unroll
                for (int nt = 0; nt < 2; ++nt)
                    pa = fmaf(fmaxf(acc[mt][nt][r] + b2v[nt], 0.f), w3v[nt], pa);
                part[r] = pa;
            }
#pragma unroll
            for (int off = 1; off < 16; off <<= 1)
#pragma unroll
                for (int r = 0; r < 4; ++r)
                    part[r] += __shfl_xor(part[r], off, 64);
            if (col == 0)
#pragma unroll
                for (int r = 0; r < 4; ++r)
                    atomicAdd(&srow[c * 64 + mt * 16 + quad * 4 + r], part[r]);
        }
    }
    __syncthreads();   // all atomics visible

    // ---- masked softmax (waves 4..7 compute harmless -inf/0 partials) ----
    float s = (t < klen) ? srow[t] : -3.4e38f;   // t>=256 -> -inf too
    float m = s;
#pragma unroll
    for (int off = 1; off < 64; off <<= 1) m = fmaxf(m, __shfl_xor(m, off, 64));
    if (lane == 0) redm[wv] = m;
    __syncthreads();
    m = fmaxf(fmaxf(redm[0], redm[1]), fmaxf(redm[2], redm[3]));
    float e = (t < klen) ? __expf(s - m) : 0.f;
    float sum = e;
#pragma unroll
    for (int off = 1; off < 64; off <<= 1) sum += __shfl_xor(sum, off, 64);
    if (lane == 0) reds[wv] = sum;
    __syncthreads();
    float denom = reds[0] + reds[1] + reds[2] + reds[3];
    if (t < TK) probs[(b * TQ + q) * TK + t] = e / denom;
}

// PV: out[b,qg+r,d=t] = sum_k probs[b,qg+r,k] * keys[b,k,t]; 4 q-rows/block.
__global__ __launch_bounds__(256) void pv(
    const float* __restrict__ probs, const float* __restrict__ keys,
    const int* __restrict__ qlens, const int* __restrict__ klens,
    float* __restrict__ out) {
    int bid = blockIdx.x;
    int b = bid >> 6, qg = (bid & 63) * 4;
    int t = threadIdx.x;
    int qlen = qlens[b], klen = klens[b];
    __shared__ float pl[4][TK];
#pragma unroll
    for (int r = 0; r < 4; ++r) {
        int q = qg + r;
        pl[r][t] = (q < qlen) ? probs[(b * TQ + q) * TK + t] : 0.f;  // never read poisoned rows
    }
    __syncthreads();
    float acc[4] = {0.f, 0.f, 0.f, 0.f};
    const float* kp = keys + b * TK * DIM + t;   // coalesced: t = channel
#pragma unroll 8
    for (int k = 0; k < klen; ++k) {
        float kv = kp[k * DIM];
#pragma unroll
        for (int r = 0; r < 4; ++r) acc[r] = fmaf(pl[r][k], kv, acc[r]);
    }
#pragma unroll
    for (int r = 0; r < 4; ++r) out[(b * TQ + qg + r) * DIM + t] = acc[r];
}

extern "C" void kernel_launch(void* const* d_in, const int* in_sizes, int n_in,
                              void* d_out, int out_size, void* d_ws, size_t ws_size,
                              hipStream_t stream) {
    (void)in_sizes; (void)n_in; (void)out_size; (void)ws_size;
    const float* queries = (const float*)d_in[0];
    const float* keys    = (const float*)d_in[1];
    const int*   qlens   = (const int*)d_in[2];
    const int*   klens   = (const int*)d_in[3];
    const float* W1      = (const float*)d_in[4];
    const float* b1      = (const float*)d_in[5];
    const float* W2      = (const float*)d_in[6];
    const float* b2      = (const float*)d_in[7];
    const float* W3      = (const float*)d_in[8];
    float* out = (float*)d_out;

    float* qkh = (float*)d_ws;                         // 2048*256 f32 = 2 MB
    float* qh = qkh;                                   // rows 0..1023
    float* kh = qkh + 1024 * HD;                       // rows 1024..2047
    unsigned short* Xh   = (unsigned short*)(qkh + 2048 * HD);   // 1 MB
    unsigned short* Xl   = Xh + 2048 * DIM;                      // 1 MB
    unsigned short* W1Th = Xl + 2048 * DIM;                      // 256 KB
    unsigned short* W1Tl = W1Th + 256 * 512;                     // 256 KB
    unsigned short* W2T  = W1Tl + 256 * 512;                     // 128 KB
    float* probs = (float*)(W2T + 256 * HD);                     // 1 MB

    pack<<<704, 256, 0, stream>>>(queries, keys, W1, W2, Xh, Xl, W1Th, W1Tl, W2T);
    prep_mfma<<<128, 256, 0, stream>>>(Xh, Xl, W1Th, W1Tl, b1, qkh);
    mlp_scores<<<BATCH * TQ, 512, 0, stream>>>(
        qh, kh, W2T, b2, W3, qlens, klens, probs);
    pv<<<BATCH * (TQ / 4), 256, 0, stream>>>(probs, keys, qlens, klens, out);
}